// Round 5
// baseline (197.135 us; speedup 1.0000x reference)
//
#include <hip/hip_runtime.h>
#include <hip/hip_bf16.h>

// Problem constants
#define Bn 2
#define Tdim 2048
#define Ddim 1024
#define Hn 16
#define HD 64

typedef unsigned short u16;
typedef unsigned int u32;
typedef __attribute__((ext_vector_type(8))) __bf16 bf16x8;
typedef __attribute__((ext_vector_type(4))) float f32x4;
typedef __attribute__((ext_vector_type(16))) float f32x16;
typedef __attribute__((ext_vector_type(4))) u32 u32x4;

struct alignas(8) U16x4 { u16 x, y, z, w; };

__device__ __forceinline__ u16 f2bf(float f) {
  union { float f; u32 i; } v; v.f = f;
  u32 x = v.i;
  u32 r = (x + 0x7fffu + ((x >> 16) & 1u)) >> 16;
  return (u16)r;
}
__device__ __forceinline__ float bf2f(u16 u) {
  union { u32 i; float f; } v; v.i = ((u32)u) << 16; return v.f;
}

// packed f32->bf16 convert: dst.lo16 = bf16(a), dst.hi16 = bf16(b) (RNE)
__device__ __forceinline__ u32 cvtpk_bf16(float a, float b) {
  u32 d;
  asm("v_cvt_pk_bf16_f32 %0, %1, %2" : "=v"(d) : "v"(a), "v"(b));
  return d;
}

// async global->LDS, 16B per lane; LDS dest = wave-uniform base + lane*16
__device__ __forceinline__ void cp16(const u16* g, u16* l) {
  __builtin_amdgcn_global_load_lds(
      (const __attribute__((address_space(1))) u32*)g,
      (__attribute__((address_space(3))) u32*)l, 16, 0, 0);
}

__device__ __forceinline__ f32x4 mfma16(bf16x8 a, bf16x8 b, f32x4 c) {
  return __builtin_amdgcn_mfma_f32_16x16x32_bf16(a, b, c, 0, 0, 0);
}
__device__ __forceinline__ f32x16 mfma32(bf16x8 a, bf16x8 b, f32x16 c) {
  return __builtin_amdgcn_mfma_f32_32x32x16_bf16(a, b, c, 0, 0, 0);
}

// ---------------- X f32 -> bf16 convert ----------------
__global__ __launch_bounds__(256) void convert_x(const float* __restrict__ src,
                                                 u16* __restrict__ dst) {
  const int i = (blockIdx.x * 256 + threadIdx.x) * 8;
  u16 t[8];
#pragma unroll
  for (int j = 0; j < 8; j++) t[j] = f2bf(src[i + j]);
  *(bf16x8*)&dst[i] = *(const bf16x8*)t;
}

// ---------------- weight transpose + f32->bf16 convert (4x 1024x1024, fused) ----------------
__global__ __launch_bounds__(256) void transpose_k(
    const float* __restrict__ s0, const float* __restrict__ s1,
    const float* __restrict__ s2, const float* __restrict__ s3,
    u16* __restrict__ dst) {
  const float* src = (blockIdx.z == 0) ? s0 : (blockIdx.z == 1) ? s1
                   : (blockIdx.z == 2) ? s2 : s3;
  u16* d = dst + (size_t)blockIdx.z * Ddim * Ddim;
  __shared__ u16 tile[32][33];
  const int tx = threadIdx.x, ty = threadIdx.y;
  const int x = blockIdx.x * 32 + tx;
  const int y0 = blockIdx.y * 32;
#pragma unroll
  for (int j = 0; j < 32; j += 8) tile[ty + j][tx] = f2bf(src[(size_t)(y0 + ty + j) * Ddim + x]);
  __syncthreads();
  const int xo = blockIdx.y * 32 + tx;
  const int yo0 = blockIdx.x * 32;
#pragma unroll
  for (int j = 0; j < 32; j += 8) d[(size_t)(yo0 + ty + j) * Ddim + xo] = tile[tx][ty + j];
}

// ---------------- fused QKV projection GEMM: 64x128 tiles for block-TLP ----------------
// BM=64: 1536 blocks (~5/CU by VGPR/LDS: 12KB LDS, ~90 VGPR) so barrier/vmcnt
// drains overlap with co-resident blocks (gemm_out at 1 block/CU had none).
// XCD-chunked swizzle: 192 consecutive logical blocks per XCD.
__global__ __launch_bounds__(256, 2) void gemm_qkv(
    const u16* __restrict__ Xb, const u16* __restrict__ WT,
    const float* __restrict__ bq, const float* __restrict__ bk, const float* __restrict__ bv,
    u16* __restrict__ Q, u16* __restrict__ K, u16* __restrict__ Vt) {
  const int flat = blockIdx.x + 64 * (blockIdx.y + 8 * blockIdx.z);
  const int l = (flat & 7) * 192 + (flat >> 3);
  const int lbx = l & 63, lby = (l >> 6) & 7, z = l >> 9;

  const u16* Wt = WT + (size_t)z * Ddim * Ddim;
  const float* bias = (z == 0) ? bq : (z == 1) ? bk : bv;
  u16* QK = (z == 0) ? Q : K;

  __shared__ alignas(16) u16 Alds[64 * 32];
  __shared__ alignas(16) u16 Blds[128 * 32];
  const int tid = threadIdx.x;
  const int w = tid >> 6, lane = tid & 63, ln = lane & 15, quad = lane >> 4;
  const int tm = lbx * 64, tn = lby * 128;

  f32x4 acc[4][2] = {};

  const int srow = tid >> 2, scol = (tid & 3) * 8;
  const u16* ag = Xb + (size_t)(tm + srow) * Ddim + scol;    // rows 0..63
  const u16* bg = Wt + (size_t)(tn + srow) * Ddim + scol;    // rows 0..63
  const u16* bg2 = bg + (size_t)64 * Ddim;                   // rows 64..127
  u16* al = &Alds[w * 512];
  u16* bl = &Blds[w * 512];
  u16* bl2 = &Blds[2048 + w * 512];

  for (int k0 = 0; k0 < Ddim; k0 += 32) {
    __syncthreads();
    cp16(ag + k0, al);
    cp16(bg + k0, bl);
    cp16(bg2 + k0, bl2);
    __syncthreads();
    bf16x8 af[4], bfr[2];
#pragma unroll
    for (int i = 0; i < 4; i++)
      af[i] = *(const bf16x8*)&Alds[(i * 16 + ln) * 32 + quad * 8];
#pragma unroll
    for (int i = 0; i < 2; i++)
      bfr[i] = *(const bf16x8*)&Blds[(w * 32 + i * 16 + ln) * 32 + quad * 8];
#pragma unroll
    for (int mi = 0; mi < 4; mi++)
#pragma unroll
      for (int ni = 0; ni < 2; ni++)
        acc[mi][ni] = mfma16(af[mi], bfr[ni], acc[mi][ni]);
  }

#pragma unroll
  for (int mi = 0; mi < 4; mi++) {
#pragma unroll
    for (int ni = 0; ni < 2; ni++) {
      const int gm0 = tm + mi * 16 + quad * 4;
      const int gn = tn + w * 32 + ni * 16 + ln;
      const float bv_ = bias[gn];
      const int hh = gn >> 6, dd = gn & 63;
      const int b0 = gm0 >> 11, t0 = gm0 & 2047;
      if (z < 2) {
        u16* p = QK + (((size_t)(b0 * Hn + hh) * Tdim) + t0) * HD + dd;
#pragma unroll
        for (int r = 0; r < 4; r++) p[r * HD] = f2bf(acc[mi][ni][r] + bv_);
      } else {
        U16x4 pk;
        pk.x = f2bf(acc[mi][ni][0] + bv_);
        pk.y = f2bf(acc[mi][ni][1] + bv_);
        pk.z = f2bf(acc[mi][ni][2] + bv_);
        pk.w = f2bf(acc[mi][ni][3] + bv_);
        *(U16x4*)&Vt[((size_t)(b0 * Hn + hh) * HD + dd) * Tdim + t0] = pk;
      }
    }
  }
}

// ---------------- flash attention (round-2 structure): triangle-folded pairing + bh-grouped XCD swizzle ----------------
// grid (512): physical id -> xcd = id&7, slot = id>>3.
// Each XCD owns 4 bh values x 16 (p,s) blocks; per-XCD K/V set = 2MB < 4MB L2
// (verified: FETCH 65->13.7MB). Uniform 8-9 tiles/block via pair (p, 15-p).
// Block-TLP beyond 2/CU measured neutral (round 4); keep 2-way key split.
#define KSTR 68
#define VSTR 132
#define L2E 1.44269504088896f
__global__ __launch_bounds__(256, 2) void attn_k(
    const u16* __restrict__ Q, const u16* __restrict__ K, const u16* __restrict__ Vt,
    u16* __restrict__ Op, float* __restrict__ lp) {
  __shared__ alignas(16) u16 Klds[128 * KSTR];
  __shared__ alignas(16) u16 Vtlds[64 * VSTR];

  const int id = blockIdx.x;
  const int xcd = id & 7, slot = id >> 3;
  const int bh = (xcd << 2) | (slot >> 4);
  const int inner = slot & 15;
  const int p = inner >> 1;
  const int s = inner & 1;
  const int tid = threadIdx.x;
  const int w = tid >> 6, lane = tid & 63;
  const int qi = lane & 31, hf = lane >> 5;

  const u16* Qh = Q + (size_t)bh * Tdim * HD;
  const u16* Kh = K + (size_t)bh * Tdim * HD;
  const u16* Vh = Vt + (size_t)bh * HD * Tdim;
  const float slope = exp2f(-0.5f * (float)((bh & 15) + 1));

  const float sl2 = slope * L2E;
  const float c1 = 0.125f * L2E;
  const float f4hf = (float)(4 * hf);
  // hoisted per-block constants for exponent folding
  float sg8[4], slm[4];
#pragma unroll
  for (int g = 0; g < 4; g++) sg8[g] = sl2 * (float)(8 * g);
#pragma unroll
  for (int m = 0; m < 4; m++) slm[m] = sl2 * (float)m;

  // the two q-tile segments of this pair, and their key-tile ranges
  const int qbs[2] = {p, 15 - p};
  int K0[2], K1[2];
#pragma unroll
  for (int seg = 0; seg < 2; seg++) {
    const int nk = qbs[seg] + 1;
    const int h0 = (nk + 1) >> 1;
    K0[seg] = s ? h0 : 0;
    K1[seg] = s ? nk : h0;
  }

  // initial prefetch: first tile of first non-empty segment
  // (segment B is never empty: nkB >= 9 so both halves >= 4 tiles)
  bf16x8 kreg[4], vreg[4];
  {
    const int kb = ((K0[0] < K1[0]) ? K0[0] : K0[1]) * 128;
#pragma unroll
    for (int c = 0; c < 4; c++) {
      const int e = c * 2048 + tid * 8;
      kreg[c] = *(const bf16x8*)&Kh[(size_t)(kb + (e >> 6)) * HD + (e & 63)];
      vreg[c] = *(const bf16x8*)&Vh[(size_t)(e >> 7) * Tdim + kb + (e & 127)];
    }
  }

  for (int seg = 0; seg < 2; seg++) {
    const int qb = qbs[seg];
    const int kt0 = K0[seg], kt1 = K1[seg];
    const int nkt = qb + 1;
    const int q0 = qb * 128;
    const int tg = q0 + w * 32 + qi;  // this lane's q-row
    const float tt2 = (slope * (float)tg + 3.0f) * L2E;

    // Q fragments (B-operand)
    bf16x8 qf[4];
#pragma unroll
    for (int kc = 0; kc < 4; kc++)
      qf[kc] = *(const bf16x8*)&Qh[(size_t)tg * HD + kc * 16 + hf * 8];

    float ls0 = 0.f, ls1 = 0.f;
    f32x16 oacc[2] = {};

    for (int kt = kt0; kt < kt1; kt++) {
      const int kb = kt * 128;
      __syncthreads();
#pragma unroll
      for (int c = 0; c < 4; c++) {
        const int e = c * 2048 + tid * 8;
        *(bf16x8*)&Klds[(e >> 6) * KSTR + (e & 63)] = kreg[c];
        *(bf16x8*)&Vtlds[(e >> 7) * VSTR + (e & 127)] = vreg[c];
      }
      __syncthreads();

      // prefetch next tile in the flattened (segA ++ segB) sequence
      {
        const int nxt = (kt + 1 < kt1) ? (kt + 1) : ((seg == 0) ? K0[1] : -1);
        if (nxt >= 0) {
          const int kb2 = nxt * 128;
#pragma unroll
          for (int c = 0; c < 4; c++) {
            const int e = c * 2048 + tid * 8;
            kreg[c] = *(const bf16x8*)&Kh[(size_t)(kb2 + (e >> 6)) * HD + (e & 63)];
            vreg[c] = *(const bf16x8*)&Vh[(size_t)(e >> 7) * Tdim + kb2 + (e & 127)];
          }
        }
      }

      // S^T = K Q^T
      f32x16 st[4] = {};
      __builtin_amdgcn_s_setprio(1);
#pragma unroll
      for (int kc = 0; kc < 4; kc++) {
#pragma unroll
        for (int ni = 0; ni < 4; ni++) {
          bf16x8 kf = *(const bf16x8*)&Klds[(ni * 32 + qi) * KSTR + kc * 16 + hf * 8];
          st[ni] = mfma32(kf, qf[kc], st[ni]);
        }
      }
      __builtin_amdgcn_s_setprio(0);

      // p = exp2(st*c1 + const(ni,g,m));  E-constants folded, diag split out
      const bool diag = (kt == nkt - 1);
      const float fkb = (float)kb + f4hf;
      bf16x8 pfrag[8];
#pragma unroll
      for (int ni = 0; ni < 4; ni++) {
        const float cni = __builtin_fmaf(sl2, fkb + (float)(32 * ni), -tt2);
        float pv[16];
        if (!diag) {
#pragma unroll
          for (int ri = 0; ri < 16; ri++) {
            const float e = __builtin_fmaf(st[ni][ri], c1, cni + sg8[ri >> 2] + slm[ri & 3]);
            const float pp = __builtin_amdgcn_exp2f(e);
            if (ri & 1) ls1 += pp; else ls0 += pp;
            pv[ri] = pp;
          }
        } else {
#pragma unroll
          for (int ri = 0; ri < 16; ri++) {
            const int n = kb + ni * 32 + (ri & 3) + 8 * (ri >> 2) + 4 * hf;
            const float e = __builtin_fmaf(st[ni][ri], c1, cni + sg8[ri >> 2] + slm[ri & 3]);
            float pp = __builtin_amdgcn_exp2f(e);
            if (n > tg) pp = 0.f;
            if (ri & 1) ls1 += pp; else ls0 += pp;
            pv[ri] = pp;
          }
        }
        // packed f32->bf16 (replaces +0x8000 round + v_perm pair-packing)
        u32 pk[4][2];
#pragma unroll
        for (int g = 0; g < 4; g++) {
          pk[g][0] = cvtpk_bf16(pv[g * 4 + 0], pv[g * 4 + 1]);
          pk[g][1] = cvtpk_bf16(pv[g * 4 + 2], pv[g * 4 + 3]);
        }
#pragma unroll
        for (int a = 0; a < 2; a++) {
          const u32 snd0 = (hf == 0) ? pk[2 * a + 1][0] : pk[2 * a][0];
          const u32 snd1 = (hf == 0) ? pk[2 * a + 1][1] : pk[2 * a][1];
          const u32 rcv0 = (u32)__shfl_xor((int)snd0, 32);
          const u32 rcv1 = (u32)__shfl_xor((int)snd1, 32);
          u32x4 fr;
          fr.x = (hf == 0) ? pk[2 * a][0] : rcv0;
          fr.y = (hf == 0) ? pk[2 * a][1] : rcv1;
          fr.z = (hf == 0) ? rcv0 : pk[2 * a + 1][0];
          fr.w = (hf == 0) ? rcv1 : pk[2 * a + 1][1];
          pfrag[ni * 2 + a] = *(bf16x8*)&fr;
        }
      }

      // O += P * V
      __builtin_amdgcn_s_setprio(1);
#pragma unroll
      for (int kf16 = 0; kf16 < 8; kf16++) {
#pragma unroll
        for (int nd = 0; nd < 2; nd++) {
          bf16x8 vf = *(const bf16x8*)&Vtlds[(nd * 32 + qi) * VSTR + kf16 * 16 + hf * 8];
          oacc[nd] = mfma32(pfrag[kf16], vf, oacc[nd]);
        }
      }
      __builtin_amdgcn_s_setprio(0);
    }

    // combine key-halves of l within wave; write partials (no normalize).
    // Empty segments (p=0, s=1, segA) still write zeros: merge sums both slots.
    float lsum = ls0 + ls1;
    lsum += __shfl_xor(lsum, 32);
    if (hf == 0) lp[(size_t)s * 65536 + bh * Tdim + tg] = lsum;

    u16* Ob = Op + (size_t)s * (32u * Tdim * HD) + ((size_t)bh * Tdim) * HD;
#pragma unroll
    for (int nd = 0; nd < 2; nd++) {
#pragma unroll
      for (int ri = 0; ri < 16; ri++) {
        const int rq = (ri & 3) + 8 * (ri >> 2) + 4 * hf;
        const int t = q0 + w * 32 + rq;
        Ob[(size_t)t * HD + nd * 32 + qi] = f2bf(oacc[nd][ri]);
      }
    }
  }
}

// ---------------- merge partials + normalize -> AO bf16 ----------------
__global__ __launch_bounds__(256) void merge_k(const u16* __restrict__ Op,
                                               const float* __restrict__ lp,
                                               u16* __restrict__ AO) {
  const int i = blockIdx.x * 256 + threadIdx.x;  // octet index
  const int d8 = i & 7;
  const int t = (i >> 3) & 2047;
  const int bh = i >> 14;
  const int b = bh >> 4, h = bh & 15;
  const float l = lp[bh * Tdim + t] + lp[65536 + bh * Tdim + t];
  const float inv = 1.0f / l;
  const size_t off = ((size_t)bh * Tdim + t) * HD + d8 * 8;
  const u16* O0 = Op + off;
  const u16* O1 = Op + (size_t)32 * Tdim * HD + off;
  u16 outv[8];
#pragma unroll
  for (int j = 0; j < 8; j++)
    outv[j] = f2bf((bf2f(O0[j]) + bf2f(O1[j])) * inv);
  *(bf16x8*)&AO[((size_t)(b * Tdim + t)) * Ddim + h * HD + d8 * 8] = *(const bf16x8*)outv;
}

// ---------------- output projection GEMM: 64x128 tiles (f32 out) ----------------
// Was 256 blocks = 1 block/CU = 4 waves/CU: zero co-resident work to cover the
// per-K-step vmcnt(0)+barrier drain. Now 512 blocks, >=4/CU by resources.
// XCD swizzle: each XCD owns one full B-panel (lby = xcd, 256KB in L2).
__global__ __launch_bounds__(256, 2) void gemm_out(
    const u16* __restrict__ A, const u16* __restrict__ WoT, const float* __restrict__ bo,
    float* __restrict__ C) {
  const int flat = blockIdx.x + 64 * blockIdx.y;
  const int l = (flat & 7) * 64 + (flat >> 3);
  const int lbx = l & 63, lby = l >> 6;

  __shared__ alignas(16) u16 Alds[64 * 32];
  __shared__ alignas(16) u16 Blds[128 * 32];
  const int tid = threadIdx.x;
  const int w = tid >> 6, lane = tid & 63, ln = lane & 15, quad = lane >> 4;
  const int tm = lbx * 64, tn = lby * 128;

  f32x4 acc[4][2] = {};

  const int srow = tid >> 2, scol = (tid & 3) * 8;
  const u16* ag = A + (size_t)(tm + srow) * Ddim + scol;
  const u16* bg = WoT + (size_t)(tn + srow) * Ddim + scol;
  const u16* bg2 = bg + (size_t)64 * Ddim;
  u16* al = &Alds[w * 512];
  u16* bl = &Blds[w * 512];
  u16* bl2 = &Blds[2048 + w * 512];

  for (int k0 = 0; k0 < Ddim; k0 += 32) {
    __syncthreads();
    cp16(ag + k0, al);
    cp16(bg + k0, bl);
    cp16(bg2 + k0, bl2);
    __syncthreads();
    bf16x8 af[4], bfr[2];
#pragma unroll
    for (int i = 0; i < 4; i++)
      af[i] = *(const bf16x8*)&Alds[(i * 16 + ln) * 32 + quad * 8];
#pragma unroll
    for (int i = 0; i < 2; i++)
      bfr[i] = *(const bf16x8*)&Blds[(w * 32 + i * 16 + ln) * 32 + quad * 8];
#pragma unroll
    for (int mi = 0; mi < 4; mi++)
#pragma unroll
      for (int ni = 0; ni < 2; ni++)
        acc[mi][ni] = mfma16(af[mi], bfr[ni], acc[mi][ni]);
  }

#pragma unroll
  for (int mi = 0; mi < 4; mi++) {
#pragma unroll
    for (int ni = 0; ni < 2; ni++) {
      const int gm0 = tm + mi * 16 + quad * 4;
      const int gn = tn + w * 32 + ni * 16 + ln;
      const float bv_ = bo[gn];
#pragma unroll
      for (int r = 0; r < 4; r++)
        C[(size_t)(gm0 + r) * Ddim + gn] = acc[mi][ni][r] + bv_;
    }
  }
}

extern "C" void kernel_launch(void* const* d_in, const int* in_sizes, int n_in,
                              void* d_out, int out_size, void* d_ws, size_t ws_size,
                              hipStream_t stream) {
  (void)in_sizes; (void)n_in; (void)out_size; (void)ws_size;
  const float* x  = (const float*)d_in[0];
  const float* Wq = (const float*)d_in[1];
  const float* bq = (const float*)d_in[2];
  const float* Wk = (const float*)d_in[3];
  const float* bk = (const float*)d_in[4];
  const float* Wv = (const float*)d_in[5];
  const float* bv = (const float*)d_in[6];
  const float* Wo = (const float*)d_in[7];
  const float* bo = (const float*)d_in[8];

  char* ws = (char*)d_ws;
  const size_t MB = 1024 * 1024;
  u16* WT   = (u16*)(ws + 0 * MB);   // 8MB: WqT, WkT, WvT, WoT (z-major)
  u16* Qb   = (u16*)(ws + 8 * MB);   // 8MB bf16 (B,H,T,64)
  u16* Kb   = (u16*)(ws + 16 * MB);
  u16* Vtb  = (u16*)(ws + 24 * MB);  // 8MB bf16 (B,H,64,T)
  u16* Xb   = (u16*)(ws + 32 * MB);  // 8MB bf16 X; overlaps AO
  u16* AO   = (u16*)(ws + 32 * MB);  // 8MB bf16 (B,T,D)
  u16* Opart= (u16*)(ws + 40 * MB);  // 16MB: 2 x (BH,T,64) bf16 partial O
  float* lpart = (float*)(ws + 56 * MB); // 512KB: 2 x (BH,T) f32 partial l
  u16* WoT = WT + (size_t)3 * Ddim * Ddim;

  convert_x<<<dim3(2048), 256, 0, stream>>>(x, Xb);
  transpose_k<<<dim3(32, 32, 4), dim3(32, 8), 0, stream>>>(Wq, Wk, Wv, Wo, WT);

  gemm_qkv<<<dim3(64, 8, 3), 256, 0, stream>>>(Xb, WT, bq, bk, bv, Qb, Kb, Vtb);
  attn_k<<<dim3(512), 256, 0, stream>>>(Qb, Kb, Vtb, Opart, lpart);
  merge_k<<<dim3(2048), 256, 0, stream>>>(Opart, lpart, AO);
  gemm_out<<<dim3(64, 8), 256, 0, stream>>>(AO, WoT, bo, (float*)d_out);
}

// Round 6
// 184.396 us; speedup vs baseline: 1.0691x; 1.0691x over previous
//
#include <hip/hip_runtime.h>
#include <hip/hip_bf16.h>

// Problem constants
#define Bn 2
#define Tdim 2048
#define Ddim 1024
#define Hn 16
#define HD 64

typedef unsigned short u16;
typedef unsigned int u32;
typedef __attribute__((ext_vector_type(8))) __bf16 bf16x8;
typedef __attribute__((ext_vector_type(4))) float f32x4;
typedef __attribute__((ext_vector_type(16))) float f32x16;
typedef __attribute__((ext_vector_type(4))) u32 u32x4;

struct alignas(8) U16x4 { u16 x, y, z, w; };

__device__ __forceinline__ u16 f2bf(float f) {
  union { float f; u32 i; } v; v.f = f;
  u32 x = v.i;
  u32 r = (x + 0x7fffu + ((x >> 16) & 1u)) >> 16;
  return (u16)r;
}
__device__ __forceinline__ float bf2f(u16 u) {
  union { u32 i; float f; } v; v.i = ((u32)u) << 16; return v.f;
}

// packed f32->bf16 convert: dst.lo16 = bf16(a), dst.hi16 = bf16(b) (RNE)
__device__ __forceinline__ u32 cvtpk_bf16(float a, float b) {
  u32 d;
  asm("v_cvt_pk_bf16_f32 %0, %1, %2" : "=v"(d) : "v"(a), "v"(b));
  return d;
}

// async global->LDS, 16B per lane; LDS dest = wave-uniform base + lane*16
__device__ __forceinline__ void cp16(const u16* g, u16* l) {
  __builtin_amdgcn_global_load_lds(
      (const __attribute__((address_space(1))) u32*)g,
      (__attribute__((address_space(3))) u32*)l, 16, 0, 0);
}

__device__ __forceinline__ f32x4 mfma16(bf16x8 a, bf16x8 b, f32x4 c) {
  return __builtin_amdgcn_mfma_f32_16x16x32_bf16(a, b, c, 0, 0, 0);
}
__device__ __forceinline__ f32x16 mfma32(bf16x8 a, bf16x8 b, f32x16 c) {
  return __builtin_amdgcn_mfma_f32_32x32x16_bf16(a, b, c, 0, 0, 0);
}

// ---------------- X f32 -> bf16 convert ----------------
__global__ __launch_bounds__(256) void convert_x(const float* __restrict__ src,
                                                 u16* __restrict__ dst) {
  const int i = (blockIdx.x * 256 + threadIdx.x) * 8;
  u16 t[8];
#pragma unroll
  for (int j = 0; j < 8; j++) t[j] = f2bf(src[i + j]);
  *(bf16x8*)&dst[i] = *(const bf16x8*)t;
}

// ---------------- weight transpose + f32->bf16 convert (4x 1024x1024, fused) ----------------
__global__ __launch_bounds__(256) void transpose_k(
    const float* __restrict__ s0, const float* __restrict__ s1,
    const float* __restrict__ s2, const float* __restrict__ s3,
    u16* __restrict__ dst) {
  const float* src = (blockIdx.z == 0) ? s0 : (blockIdx.z == 1) ? s1
                   : (blockIdx.z == 2) ? s2 : s3;
  u16* d = dst + (size_t)blockIdx.z * Ddim * Ddim;
  __shared__ u16 tile[32][33];
  const int tx = threadIdx.x, ty = threadIdx.y;
  const int x = blockIdx.x * 32 + tx;
  const int y0 = blockIdx.y * 32;
#pragma unroll
  for (int j = 0; j < 32; j += 8) tile[ty + j][tx] = f2bf(src[(size_t)(y0 + ty + j) * Ddim + x]);
  __syncthreads();
  const int xo = blockIdx.y * 32 + tx;
  const int yo0 = blockIdx.x * 32;
#pragma unroll
  for (int j = 0; j < 32; j += 8) d[(size_t)(yo0 + ty + j) * Ddim + xo] = tile[tx][ty + j];
}

// ---------------- fused QKV projection GEMM (128x128 tiles, reverted) ----------------
// Round-5 A/B: BM=64 regressed this kernel 31->53us (MfmaUtil 18%, FETCH 2x).
// The 128x128 / 768-block / 3-per-CU shape is the m97-structure sweet spot.
// XCD-chunked swizzle: 96 consecutive logical blocks per XCD.
__global__ __launch_bounds__(256, 2) void gemm_qkv(
    const u16* __restrict__ Xb, const u16* __restrict__ WT,
    const float* __restrict__ bq, const float* __restrict__ bk, const float* __restrict__ bv,
    u16* __restrict__ Q, u16* __restrict__ K, u16* __restrict__ Vt) {
  const int flat = blockIdx.x + 32 * (blockIdx.y + 8 * blockIdx.z);
  const int l = (flat & 7) * 96 + (flat >> 3);
  const int lbx = l & 31, lby = (l >> 5) & 7, z = l >> 8;

  const u16* Wt = WT + (size_t)z * Ddim * Ddim;
  const float* bias = (z == 0) ? bq : (z == 1) ? bk : bv;
  u16* QK = (z == 0) ? Q : K;

  __shared__ alignas(16) u16 Alds[128 * 32];
  __shared__ alignas(16) u16 Blds[128 * 32];
  const int tid = threadIdx.x;
  const int w = tid >> 6, lane = tid & 63, ln = lane & 15, quad = lane >> 4;
  const int wm = (w >> 1) * 64, wn = (w & 1) * 64;
  const int tm = lbx * 128, tn = lby * 128;

  f32x4 acc[4][4] = {};

  const int srow = tid >> 2, scol = (tid & 3) * 8;
  const u16* ag = Xb + (size_t)(tm + srow) * Ddim + scol;
  const u16* ag2 = ag + (size_t)64 * Ddim;
  const u16* bg = Wt + (size_t)(tn + srow) * Ddim + scol;
  const u16* bg2 = bg + (size_t)64 * Ddim;
  u16* al = &Alds[w * 512];
  u16* al2 = &Alds[2048 + w * 512];
  u16* bl = &Blds[w * 512];
  u16* bl2 = &Blds[2048 + w * 512];

  for (int k0 = 0; k0 < Ddim; k0 += 32) {
    __syncthreads();
    cp16(ag + k0, al);
    cp16(ag2 + k0, al2);
    cp16(bg + k0, bl);
    cp16(bg2 + k0, bl2);
    __syncthreads();
    bf16x8 af[4], bfr[4];
#pragma unroll
    for (int i = 0; i < 4; i++)
      af[i] = *(const bf16x8*)&Alds[(wm + i * 16 + ln) * 32 + quad * 8];
#pragma unroll
    for (int i = 0; i < 4; i++)
      bfr[i] = *(const bf16x8*)&Blds[(wn + i * 16 + ln) * 32 + quad * 8];
#pragma unroll
    for (int mi = 0; mi < 4; mi++)
#pragma unroll
      for (int ni = 0; ni < 4; ni++)
        acc[mi][ni] = mfma16(af[mi], bfr[ni], acc[mi][ni]);
  }

#pragma unroll
  for (int mi = 0; mi < 4; mi++) {
#pragma unroll
    for (int ni = 0; ni < 4; ni++) {
      const int gm0 = tm + wm + mi * 16 + quad * 4;
      const int gn = tn + wn + ni * 16 + ln;
      const float bv_ = bias[gn];
      const int hh = gn >> 6, dd = gn & 63;
      const int b0 = gm0 >> 11, t0 = gm0 & 2047;
      if (z < 2) {
        u16* p = QK + (((size_t)(b0 * Hn + hh) * Tdim) + t0) * HD + dd;
#pragma unroll
        for (int r = 0; r < 4; r++) p[r * HD] = f2bf(acc[mi][ni][r] + bv_);
      } else {
        U16x4 pk;
        pk.x = f2bf(acc[mi][ni][0] + bv_);
        pk.y = f2bf(acc[mi][ni][1] + bv_);
        pk.z = f2bf(acc[mi][ni][2] + bv_);
        pk.w = f2bf(acc[mi][ni][3] + bv_);
        *(U16x4*)&Vt[((size_t)(b0 * Hn + hh) * HD + dd) * Tdim + t0] = pk;
      }
    }
  }
}

// ---------------- flash attention: triangle-folded pairing + bh-grouped XCD swizzle ----------------
// grid (512): physical id -> xcd = id&7, slot = id>>3.
// Each XCD owns 4 bh values x 16 (p,s) blocks; per-XCD K/V set = 2MB < 4MB L2
// (verified: FETCH 65->13.7MB). Uniform 8-9 tiles/block via pair (p, 15-p).
// Block-TLP beyond 2/CU measured neutral (round 4); keep 2-way key split.
#define KSTR 68
#define VSTR 132
#define L2E 1.44269504088896f
__global__ __launch_bounds__(256, 2) void attn_k(
    const u16* __restrict__ Q, const u16* __restrict__ K, const u16* __restrict__ Vt,
    u16* __restrict__ Op, float* __restrict__ lp) {
  __shared__ alignas(16) u16 Klds[128 * KSTR];
  __shared__ alignas(16) u16 Vtlds[64 * VSTR];

  const int id = blockIdx.x;
  const int xcd = id & 7, slot = id >> 3;
  const int bh = (xcd << 2) | (slot >> 4);
  const int inner = slot & 15;
  const int p = inner >> 1;
  const int s = inner & 1;
  const int tid = threadIdx.x;
  const int w = tid >> 6, lane = tid & 63;
  const int qi = lane & 31, hf = lane >> 5;

  const u16* Qh = Q + (size_t)bh * Tdim * HD;
  const u16* Kh = K + (size_t)bh * Tdim * HD;
  const u16* Vh = Vt + (size_t)bh * HD * Tdim;
  const float slope = exp2f(-0.5f * (float)((bh & 15) + 1));

  const float sl2 = slope * L2E;
  const float c1 = 0.125f * L2E;
  const float f4hf = (float)(4 * hf);
  // hoisted per-block constants for exponent folding
  float sg8[4], slm[4];
#pragma unroll
  for (int g = 0; g < 4; g++) sg8[g] = sl2 * (float)(8 * g);
#pragma unroll
  for (int m = 0; m < 4; m++) slm[m] = sl2 * (float)m;

  // the two q-tile segments of this pair, and their key-tile ranges
  const int qbs[2] = {p, 15 - p};
  int K0[2], K1[2];
#pragma unroll
  for (int seg = 0; seg < 2; seg++) {
    const int nk = qbs[seg] + 1;
    const int h0 = (nk + 1) >> 1;
    K0[seg] = s ? h0 : 0;
    K1[seg] = s ? nk : h0;
  }

  // initial prefetch: first tile of first non-empty segment
  // (segment B is never empty: nkB >= 9 so both halves >= 4 tiles)
  bf16x8 kreg[4], vreg[4];
  {
    const int kb = ((K0[0] < K1[0]) ? K0[0] : K0[1]) * 128;
#pragma unroll
    for (int c = 0; c < 4; c++) {
      const int e = c * 2048 + tid * 8;
      kreg[c] = *(const bf16x8*)&Kh[(size_t)(kb + (e >> 6)) * HD + (e & 63)];
      vreg[c] = *(const bf16x8*)&Vh[(size_t)(e >> 7) * Tdim + kb + (e & 127)];
    }
  }

  for (int seg = 0; seg < 2; seg++) {
    const int qb = qbs[seg];
    const int kt0 = K0[seg], kt1 = K1[seg];
    const int nkt = qb + 1;
    const int q0 = qb * 128;
    const int tg = q0 + w * 32 + qi;  // this lane's q-row
    const float tt2 = (slope * (float)tg + 3.0f) * L2E;

    // Q fragments (B-operand)
    bf16x8 qf[4];
#pragma unroll
    for (int kc = 0; kc < 4; kc++)
      qf[kc] = *(const bf16x8*)&Qh[(size_t)tg * HD + kc * 16 + hf * 8];

    float ls0 = 0.f, ls1 = 0.f;
    f32x16 oacc[2] = {};

    for (int kt = kt0; kt < kt1; kt++) {
      const int kb = kt * 128;
      __syncthreads();
#pragma unroll
      for (int c = 0; c < 4; c++) {
        const int e = c * 2048 + tid * 8;
        *(bf16x8*)&Klds[(e >> 6) * KSTR + (e & 63)] = kreg[c];
        *(bf16x8*)&Vtlds[(e >> 7) * VSTR + (e & 127)] = vreg[c];
      }
      __syncthreads();

      // prefetch next tile in the flattened (segA ++ segB) sequence
      {
        const int nxt = (kt + 1 < kt1) ? (kt + 1) : ((seg == 0) ? K0[1] : -1);
        if (nxt >= 0) {
          const int kb2 = nxt * 128;
#pragma unroll
          for (int c = 0; c < 4; c++) {
            const int e = c * 2048 + tid * 8;
            kreg[c] = *(const bf16x8*)&Kh[(size_t)(kb2 + (e >> 6)) * HD + (e & 63)];
            vreg[c] = *(const bf16x8*)&Vh[(size_t)(e >> 7) * Tdim + kb2 + (e & 127)];
          }
        }
      }

      // S^T = K Q^T
      f32x16 st[4] = {};
      __builtin_amdgcn_s_setprio(1);
#pragma unroll
      for (int kc = 0; kc < 4; kc++) {
#pragma unroll
        for (int ni = 0; ni < 4; ni++) {
          bf16x8 kf = *(const bf16x8*)&Klds[(ni * 32 + qi) * KSTR + kc * 16 + hf * 8];
          st[ni] = mfma32(kf, qf[kc], st[ni]);
        }
      }
      __builtin_amdgcn_s_setprio(0);

      // p = exp2(st*c1 + const(ni,g,m));  E-constants folded, diag split out
      const bool diag = (kt == nkt - 1);
      const float fkb = (float)kb + f4hf;
      bf16x8 pfrag[8];
#pragma unroll
      for (int ni = 0; ni < 4; ni++) {
        const float cni = __builtin_fmaf(sl2, fkb + (float)(32 * ni), -tt2);
        float pv[16];
        if (!diag) {
#pragma unroll
          for (int ri = 0; ri < 16; ri++) {
            const float e = __builtin_fmaf(st[ni][ri], c1, cni + sg8[ri >> 2] + slm[ri & 3]);
            const float pp = __builtin_amdgcn_exp2f(e);
            if (ri & 1) ls1 += pp; else ls0 += pp;
            pv[ri] = pp;
          }
        } else {
#pragma unroll
          for (int ri = 0; ri < 16; ri++) {
            const int n = kb + ni * 32 + (ri & 3) + 8 * (ri >> 2) + 4 * hf;
            const float e = __builtin_fmaf(st[ni][ri], c1, cni + sg8[ri >> 2] + slm[ri & 3]);
            float pp = __builtin_amdgcn_exp2f(e);
            if (n > tg) pp = 0.f;
            if (ri & 1) ls1 += pp; else ls0 += pp;
            pv[ri] = pp;
          }
        }
        // packed f32->bf16 (replaces +0x8000 round + v_perm pair-packing)
        u32 pk[4][2];
#pragma unroll
        for (int g = 0; g < 4; g++) {
          pk[g][0] = cvtpk_bf16(pv[g * 4 + 0], pv[g * 4 + 1]);
          pk[g][1] = cvtpk_bf16(pv[g * 4 + 2], pv[g * 4 + 3]);
        }
#pragma unroll
        for (int a = 0; a < 2; a++) {
          const u32 snd0 = (hf == 0) ? pk[2 * a + 1][0] : pk[2 * a][0];
          const u32 snd1 = (hf == 0) ? pk[2 * a + 1][1] : pk[2 * a][1];
          const u32 rcv0 = (u32)__shfl_xor((int)snd0, 32);
          const u32 rcv1 = (u32)__shfl_xor((int)snd1, 32);
          u32x4 fr;
          fr.x = (hf == 0) ? pk[2 * a][0] : rcv0;
          fr.y = (hf == 0) ? pk[2 * a][1] : rcv1;
          fr.z = (hf == 0) ? rcv0 : pk[2 * a + 1][0];
          fr.w = (hf == 0) ? rcv1 : pk[2 * a + 1][1];
          pfrag[ni * 2 + a] = *(bf16x8*)&fr;
        }
      }

      // O += P * V
      __builtin_amdgcn_s_setprio(1);
#pragma unroll
      for (int kf16 = 0; kf16 < 8; kf16++) {
#pragma unroll
        for (int nd = 0; nd < 2; nd++) {
          bf16x8 vf = *(const bf16x8*)&Vtlds[(nd * 32 + qi) * VSTR + kf16 * 16 + hf * 8];
          oacc[nd] = mfma32(pfrag[kf16], vf, oacc[nd]);
        }
      }
      __builtin_amdgcn_s_setprio(0);
    }

    // combine key-halves of l within wave; write partials (no normalize).
    // Empty segments (p=0, s=1, segA) still write zeros: merge sums both slots.
    float lsum = ls0 + ls1;
    lsum += __shfl_xor(lsum, 32);
    if (hf == 0) lp[(size_t)s * 65536 + bh * Tdim + tg] = lsum;

    u16* Ob = Op + (size_t)s * (32u * Tdim * HD) + ((size_t)bh * Tdim) * HD;
#pragma unroll
    for (int nd = 0; nd < 2; nd++) {
#pragma unroll
      for (int ri = 0; ri < 16; ri++) {
        const int rq = (ri & 3) + 8 * (ri >> 2) + 4 * hf;
        const int t = q0 + w * 32 + rq;
        Ob[(size_t)t * HD + nd * 32 + qi] = f2bf(oacc[nd][ri]);
      }
    }
  }
}

// ---------------- merge partials + normalize -> AO bf16 ----------------
__global__ __launch_bounds__(256) void merge_k(const u16* __restrict__ Op,
                                               const float* __restrict__ lp,
                                               u16* __restrict__ AO) {
  const int i = blockIdx.x * 256 + threadIdx.x;  // octet index
  const int d8 = i & 7;
  const int t = (i >> 3) & 2047;
  const int bh = i >> 14;
  const int b = bh >> 4, h = bh & 15;
  const float l = lp[bh * Tdim + t] + lp[65536 + bh * Tdim + t];
  const float inv = 1.0f / l;
  const size_t off = ((size_t)bh * Tdim + t) * HD + d8 * 8;
  const u16* O0 = Op + off;
  const u16* O1 = Op + (size_t)32 * Tdim * HD + off;
  u16 outv[8];
#pragma unroll
  for (int j = 0; j < 8; j++)
    outv[j] = f2bf((bf2f(O0[j]) + bf2f(O1[j])) * inv);
  *(bf16x8*)&AO[((size_t)(b * Tdim + t)) * Ddim + h * HD + d8 * 8] = *(const bf16x8*)outv;
}

// ---------------- output projection GEMM: 64x128 tiles (f32 out) ----------------
// KEPT from round 5: at 128x128 this kernel was 256 blocks = 1 block/CU with
// zero co-resident work to cover vmcnt(0)+barrier drains (~35us). At 64x128 =
// 512 blocks = 2/CU it improved ~15us (round-5 ledger). gemm_qkv does NOT
// benefit from this (768 blocks = 3/CU already; BM=64 there regressed).
// XCD swizzle: each XCD owns one full B-panel (lby = xcd, 256KB in L2).
__global__ __launch_bounds__(256, 2) void gemm_out(
    const u16* __restrict__ A, const u16* __restrict__ WoT, const float* __restrict__ bo,
    float* __restrict__ C) {
  const int flat = blockIdx.x + 64 * blockIdx.y;
  const int l = (flat & 7) * 64 + (flat >> 3);
  const int lbx = l & 63, lby = l >> 6;

  __shared__ alignas(16) u16 Alds[64 * 32];
  __shared__ alignas(16) u16 Blds[128 * 32];
  const int tid = threadIdx.x;
  const int w = tid >> 6, lane = tid & 63, ln = lane & 15, quad = lane >> 4;
  const int tm = lbx * 64, tn = lby * 128;

  f32x4 acc[4][2] = {};

  const int srow = tid >> 2, scol = (tid & 3) * 8;
  const u16* ag = A + (size_t)(tm + srow) * Ddim + scol;
  const u16* bg = WoT + (size_t)(tn + srow) * Ddim + scol;
  const u16* bg2 = bg + (size_t)64 * Ddim;
  u16* al = &Alds[w * 512];
  u16* bl = &Blds[w * 512];
  u16* bl2 = &Blds[2048 + w * 512];

  for (int k0 = 0; k0 < Ddim; k0 += 32) {
    __syncthreads();
    cp16(ag + k0, al);
    cp16(bg + k0, bl);
    cp16(bg2 + k0, bl2);
    __syncthreads();
    bf16x8 af[4], bfr[2];
#pragma unroll
    for (int i = 0; i < 4; i++)
      af[i] = *(const bf16x8*)&Alds[(i * 16 + ln) * 32 + quad * 8];
#pragma unroll
    for (int i = 0; i < 2; i++)
      bfr[i] = *(const bf16x8*)&Blds[(w * 32 + i * 16 + ln) * 32 + quad * 8];
#pragma unroll
    for (int mi = 0; mi < 4; mi++)
#pragma unroll
      for (int ni = 0; ni < 2; ni++)
        acc[mi][ni] = mfma16(af[mi], bfr[ni], acc[mi][ni]);
  }

#pragma unroll
  for (int mi = 0; mi < 4; mi++) {
#pragma unroll
    for (int ni = 0; ni < 2; ni++) {
      const int gm0 = tm + mi * 16 + quad * 4;
      const int gn = tn + w * 32 + ni * 16 + ln;
      const float bv_ = bo[gn];
#pragma unroll
      for (int r = 0; r < 4; r++)
        C[(size_t)(gm0 + r) * Ddim + gn] = acc[mi][ni][r] + bv_;
    }
  }
}

extern "C" void kernel_launch(void* const* d_in, const int* in_sizes, int n_in,
                              void* d_out, int out_size, void* d_ws, size_t ws_size,
                              hipStream_t stream) {
  (void)in_sizes; (void)n_in; (void)out_size; (void)ws_size;
  const float* x  = (const float*)d_in[0];
  const float* Wq = (const float*)d_in[1];
  const float* bq = (const float*)d_in[2];
  const float* Wk = (const float*)d_in[3];
  const float* bk = (const float*)d_in[4];
  const float* Wv = (const float*)d_in[5];
  const float* bv = (const float*)d_in[6];
  const float* Wo = (const float*)d_in[7];
  const float* bo = (const float*)d_in[8];

  char* ws = (char*)d_ws;
  const size_t MB = 1024 * 1024;
  u16* WT   = (u16*)(ws + 0 * MB);   // 8MB: WqT, WkT, WvT, WoT (z-major)
  u16* Qb   = (u16*)(ws + 8 * MB);   // 8MB bf16 (B,H,T,64)
  u16* Kb   = (u16*)(ws + 16 * MB);
  u16* Vtb  = (u16*)(ws + 24 * MB);  // 8MB bf16 (B,H,64,T)
  u16* Xb   = (u16*)(ws + 32 * MB);  // 8MB bf16 X; overlaps AO
  u16* AO   = (u16*)(ws + 32 * MB);  // 8MB bf16 (B,T,D)
  u16* Opart= (u16*)(ws + 40 * MB);  // 16MB: 2 x (BH,T,64) bf16 partial O
  float* lpart = (float*)(ws + 56 * MB); // 512KB: 2 x (BH,T) f32 partial l
  u16* WoT = WT + (size_t)3 * Ddim * Ddim;

  convert_x<<<dim3(2048), 256, 0, stream>>>(x, Xb);
  transpose_k<<<dim3(32, 32, 4), dim3(32, 8), 0, stream>>>(Wq, Wk, Wv, Wo, WT);

  gemm_qkv<<<dim3(32, 8, 3), 256, 0, stream>>>(Xb, WT, bq, bk, bv, Qb, Kb, Vtb);
  attn_k<<<dim3(512), 256, 0, stream>>>(Qb, Kb, Vtb, Opart, lpart);
  merge_k<<<dim3(2048), 256, 0, stream>>>(Opart, lpart, AO);
  gemm_out<<<dim3(64, 8), 256, 0, stream>>>(AO, WoT, bo, (float*)d_out);
}

// Round 7
// 182.718 us; speedup vs baseline: 1.0789x; 1.0092x over previous
//
#include <hip/hip_runtime.h>
#include <hip/hip_bf16.h>

// Problem constants
#define Bn 2
#define Tdim 2048
#define Ddim 1024
#define Hn 16
#define HD 64

typedef unsigned short u16;
typedef unsigned int u32;
typedef __attribute__((ext_vector_type(8))) __bf16 bf16x8;
typedef __attribute__((ext_vector_type(4))) float f32x4;
typedef __attribute__((ext_vector_type(16))) float f32x16;
typedef __attribute__((ext_vector_type(4))) u32 u32x4;

struct alignas(8) U16x4 { u16 x, y, z, w; };

__device__ __forceinline__ u16 f2bf(float f) {
  union { float f; u32 i; } v; v.f = f;
  u32 x = v.i;
  u32 r = (x + 0x7fffu + ((x >> 16) & 1u)) >> 16;
  return (u16)r;
}
__device__ __forceinline__ float bf2f(u16 u) {
  union { u32 i; float f; } v; v.i = ((u32)u) << 16; return v.f;
}

// packed f32->bf16 convert: dst.lo16 = bf16(a), dst.hi16 = bf16(b) (RNE)
__device__ __forceinline__ u32 cvtpk_bf16(float a, float b) {
  u32 d;
  asm("v_cvt_pk_bf16_f32 %0, %1, %2" : "=v"(d) : "v"(a), "v"(b));
  return d;
}

// async global->LDS, 16B per lane; LDS dest = wave-uniform base + lane*16
__device__ __forceinline__ void cp16(const u16* g, u16* l) {
  __builtin_amdgcn_global_load_lds(
      (const __attribute__((address_space(1))) u32*)g,
      (__attribute__((address_space(3))) u32*)l, 16, 0, 0);
}

__device__ __forceinline__ f32x4 mfma16(bf16x8 a, bf16x8 b, f32x4 c) {
  return __builtin_amdgcn_mfma_f32_16x16x32_bf16(a, b, c, 0, 0, 0);
}
__device__ __forceinline__ f32x16 mfma32(bf16x8 a, bf16x8 b, f32x16 c) {
  return __builtin_amdgcn_mfma_f32_32x32x16_bf16(a, b, c, 0, 0, 0);
}

// ---------------- X f32 -> bf16 convert ----------------
__global__ __launch_bounds__(256) void convert_x(const float* __restrict__ src,
                                                 u16* __restrict__ dst) {
  const int i = (blockIdx.x * 256 + threadIdx.x) * 8;
  u16 t[8];
#pragma unroll
  for (int j = 0; j < 8; j++) t[j] = f2bf(src[i + j]);
  *(bf16x8*)&dst[i] = *(const bf16x8*)t;
}

// ---------------- weight transpose + f32->bf16 convert (4x 1024x1024, fused) ----------------
__global__ __launch_bounds__(256) void transpose_k(
    const float* __restrict__ s0, const float* __restrict__ s1,
    const float* __restrict__ s2, const float* __restrict__ s3,
    u16* __restrict__ dst) {
  const float* src = (blockIdx.z == 0) ? s0 : (blockIdx.z == 1) ? s1
                   : (blockIdx.z == 2) ? s2 : s3;
  u16* d = dst + (size_t)blockIdx.z * Ddim * Ddim;
  __shared__ u16 tile[32][33];
  const int tx = threadIdx.x, ty = threadIdx.y;
  const int x = blockIdx.x * 32 + tx;
  const int y0 = blockIdx.y * 32;
#pragma unroll
  for (int j = 0; j < 32; j += 8) tile[ty + j][tx] = f2bf(src[(size_t)(y0 + ty + j) * Ddim + x]);
  __syncthreads();
  const int xo = blockIdx.y * 32 + tx;
  const int yo0 = blockIdx.x * 32;
#pragma unroll
  for (int j = 0; j < 32; j += 8) d[(size_t)(yo0 + ty + j) * Ddim + xo] = tile[tx][ty + j];
}

// ---------------- fused QKV projection GEMM: 128x128, BK=64, swizzled LDS ----------------
// Round-6 PMC: 48us, MfmaUtil 20%, 3.1M LDS bank conflicts. Cause: [128][32]
// tile = 64B rows -> only 2 bank phases -> 8-way conflict on ds_read_b128.
// Fix (T2 + rule #21): BK=64 (128B rows), LDS slot ^= (row&7); gload_lds dest
// stays LINEAR, the global SOURCE col is pre-swizzled (lane&7)^(lane>>3), and
// reads apply the same XOR ((k2*4+quad)^(ln&7)). Bonus: barriers halve (16
// K-steps). LDS 32KB/block, 768 blocks = 3/CU.
__global__ __launch_bounds__(256, 2) void gemm_qkv(
    const u16* __restrict__ Xb, const u16* __restrict__ WT,
    const float* __restrict__ bq, const float* __restrict__ bk, const float* __restrict__ bv,
    u16* __restrict__ Q, u16* __restrict__ K, u16* __restrict__ Vt) {
  const int flat = blockIdx.x + 32 * (blockIdx.y + 8 * blockIdx.z);
  const int l = (flat & 7) * 96 + (flat >> 3);
  const int lbx = l & 31, lby = (l >> 5) & 7, z = l >> 8;

  const u16* Wt = WT + (size_t)z * Ddim * Ddim;
  const float* bias = (z == 0) ? bq : (z == 1) ? bk : bv;
  u16* QK = (z == 0) ? Q : K;

  __shared__ alignas(16) u16 Alds[128 * 64];
  __shared__ alignas(16) u16 Blds[128 * 64];
  const int tid = threadIdx.x;
  const int w = tid >> 6, lane = tid & 63, ln = lane & 15, quad = lane >> 4;
  const int wm = (w >> 1) * 64, wn = (w & 1) * 64;
  const int tm = lbx * 128, tn = lby * 128;

  f32x4 acc[4][4] = {};

  // staging: wave w, set j covers rows w*32 + j*8 + (lane>>3); source col
  // pre-swizzled so LDS(row, slot) holds global col16 = slot ^ (row&7).
  const int srow = lane >> 3;                    // 0..7
  const int scol = ((lane & 7) ^ srow) * 8;      // inverse swizzle on source
  const u16* ag0 = Xb + (size_t)(tm + w * 32 + srow) * Ddim + scol;
  const u16* bg0 = Wt + (size_t)(tn + w * 32 + srow) * Ddim + scol;

  for (int k0 = 0; k0 < Ddim; k0 += 64) {
    __syncthreads();
#pragma unroll
    for (int j = 0; j < 4; j++) {
      cp16(ag0 + (size_t)j * 8 * Ddim + k0, &Alds[(w * 32 + j * 8) * 64]);
      cp16(bg0 + (size_t)j * 8 * Ddim + k0, &Blds[(w * 32 + j * 8) * 64]);
    }
    __syncthreads();
#pragma unroll
    for (int k2 = 0; k2 < 2; k2++) {
      const int so = ((k2 * 4 + quad) ^ (ln & 7)) * 8;  // swizzled read slot
      bf16x8 af[4], bfr[4];
#pragma unroll
      for (int i = 0; i < 4; i++)
        af[i] = *(const bf16x8*)&Alds[(wm + i * 16 + ln) * 64 + so];
#pragma unroll
      for (int i = 0; i < 4; i++)
        bfr[i] = *(const bf16x8*)&Blds[(wn + i * 16 + ln) * 64 + so];
#pragma unroll
      for (int mi = 0; mi < 4; mi++)
#pragma unroll
        for (int ni = 0; ni < 4; ni++)
          acc[mi][ni] = mfma16(af[mi], bfr[ni], acc[mi][ni]);
    }
  }

#pragma unroll
  for (int mi = 0; mi < 4; mi++) {
#pragma unroll
    for (int ni = 0; ni < 4; ni++) {
      const int gm0 = tm + wm + mi * 16 + quad * 4;
      const int gn = tn + wn + ni * 16 + ln;
      const float bv_ = bias[gn];
      const int hh = gn >> 6, dd = gn & 63;
      const int b0 = gm0 >> 11, t0 = gm0 & 2047;
      if (z < 2) {
        u16* p = QK + (((size_t)(b0 * Hn + hh) * Tdim) + t0) * HD + dd;
#pragma unroll
        for (int r = 0; r < 4; r++) p[r * HD] = f2bf(acc[mi][ni][r] + bv_);
      } else {
        U16x4 pk;
        pk.x = f2bf(acc[mi][ni][0] + bv_);
        pk.y = f2bf(acc[mi][ni][1] + bv_);
        pk.z = f2bf(acc[mi][ni][2] + bv_);
        pk.w = f2bf(acc[mi][ni][3] + bv_);
        *(U16x4*)&Vt[((size_t)(b0 * Hn + hh) * HD + dd) * Tdim + t0] = pk;
      }
    }
  }
}

// ---------------- flash attention: triangle-folded pairing + bh-grouped XCD swizzle ----------------
// grid (512): physical id -> xcd = id&7, slot = id>>3.
// Each XCD owns 4 bh values x 16 (p,s) blocks; per-XCD K/V set = 2MB < 4MB L2
// (verified: FETCH 65->13.7MB). Uniform 8-9 tiles/block via pair (p, 15-p).
// Block-TLP beyond 2/CU measured neutral (round 4); keep 2-way key split.
#define KSTR 68
#define VSTR 132
#define L2E 1.44269504088896f
__global__ __launch_bounds__(256, 2) void attn_k(
    const u16* __restrict__ Q, const u16* __restrict__ K, const u16* __restrict__ Vt,
    u16* __restrict__ Op, float* __restrict__ lp) {
  __shared__ alignas(16) u16 Klds[128 * KSTR];
  __shared__ alignas(16) u16 Vtlds[64 * VSTR];

  const int id = blockIdx.x;
  const int xcd = id & 7, slot = id >> 3;
  const int bh = (xcd << 2) | (slot >> 4);
  const int inner = slot & 15;
  const int p = inner >> 1;
  const int s = inner & 1;
  const int tid = threadIdx.x;
  const int w = tid >> 6, lane = tid & 63;
  const int qi = lane & 31, hf = lane >> 5;

  const u16* Qh = Q + (size_t)bh * Tdim * HD;
  const u16* Kh = K + (size_t)bh * Tdim * HD;
  const u16* Vh = Vt + (size_t)bh * HD * Tdim;
  const float slope = exp2f(-0.5f * (float)((bh & 15) + 1));

  const float sl2 = slope * L2E;
  const float c1 = 0.125f * L2E;
  const float f4hf = (float)(4 * hf);
  // hoisted per-block constants for exponent folding
  float sg8[4], slm[4];
#pragma unroll
  for (int g = 0; g < 4; g++) sg8[g] = sl2 * (float)(8 * g);
#pragma unroll
  for (int m = 0; m < 4; m++) slm[m] = sl2 * (float)m;

  // the two q-tile segments of this pair, and their key-tile ranges
  const int qbs[2] = {p, 15 - p};
  int K0[2], K1[2];
#pragma unroll
  for (int seg = 0; seg < 2; seg++) {
    const int nk = qbs[seg] + 1;
    const int h0 = (nk + 1) >> 1;
    K0[seg] = s ? h0 : 0;
    K1[seg] = s ? nk : h0;
  }

  // initial prefetch: first tile of first non-empty segment
  // (segment B is never empty: nkB >= 9 so both halves >= 4 tiles)
  bf16x8 kreg[4], vreg[4];
  {
    const int kb = ((K0[0] < K1[0]) ? K0[0] : K0[1]) * 128;
#pragma unroll
    for (int c = 0; c < 4; c++) {
      const int e = c * 2048 + tid * 8;
      kreg[c] = *(const bf16x8*)&Kh[(size_t)(kb + (e >> 6)) * HD + (e & 63)];
      vreg[c] = *(const bf16x8*)&Vh[(size_t)(e >> 7) * Tdim + kb + (e & 127)];
    }
  }

  for (int seg = 0; seg < 2; seg++) {
    const int qb = qbs[seg];
    const int kt0 = K0[seg], kt1 = K1[seg];
    const int nkt = qb + 1;
    const int q0 = qb * 128;
    const int tg = q0 + w * 32 + qi;  // this lane's q-row
    const float tt2 = (slope * (float)tg + 3.0f) * L2E;

    // Q fragments (B-operand)
    bf16x8 qf[4];
#pragma unroll
    for (int kc = 0; kc < 4; kc++)
      qf[kc] = *(const bf16x8*)&Qh[(size_t)tg * HD + kc * 16 + hf * 8];

    float ls0 = 0.f, ls1 = 0.f;
    f32x16 oacc[2] = {};

    for (int kt = kt0; kt < kt1; kt++) {
      const int kb = kt * 128;
      __syncthreads();
#pragma unroll
      for (int c = 0; c < 4; c++) {
        const int e = c * 2048 + tid * 8;
        *(bf16x8*)&Klds[(e >> 6) * KSTR + (e & 63)] = kreg[c];
        *(bf16x8*)&Vtlds[(e >> 7) * VSTR + (e & 127)] = vreg[c];
      }
      __syncthreads();

      // prefetch next tile in the flattened (segA ++ segB) sequence
      {
        const int nxt = (kt + 1 < kt1) ? (kt + 1) : ((seg == 0) ? K0[1] : -1);
        if (nxt >= 0) {
          const int kb2 = nxt * 128;
#pragma unroll
          for (int c = 0; c < 4; c++) {
            const int e = c * 2048 + tid * 8;
            kreg[c] = *(const bf16x8*)&Kh[(size_t)(kb2 + (e >> 6)) * HD + (e & 63)];
            vreg[c] = *(const bf16x8*)&Vh[(size_t)(e >> 7) * Tdim + kb2 + (e & 127)];
          }
        }
      }

      // S^T = K Q^T
      f32x16 st[4] = {};
      __builtin_amdgcn_s_setprio(1);
#pragma unroll
      for (int kc = 0; kc < 4; kc++) {
#pragma unroll
        for (int ni = 0; ni < 4; ni++) {
          bf16x8 kf = *(const bf16x8*)&Klds[(ni * 32 + qi) * KSTR + kc * 16 + hf * 8];
          st[ni] = mfma32(kf, qf[kc], st[ni]);
        }
      }
      __builtin_amdgcn_s_setprio(0);

      // p = exp2(st*c1 + const(ni,g,m));  E-constants folded, diag split out
      const bool diag = (kt == nkt - 1);
      const float fkb = (float)kb + f4hf;
      bf16x8 pfrag[8];
#pragma unroll
      for (int ni = 0; ni < 4; ni++) {
        const float cni = __builtin_fmaf(sl2, fkb + (float)(32 * ni), -tt2);
        float pv[16];
        if (!diag) {
#pragma unroll
          for (int ri = 0; ri < 16; ri++) {
            const float e = __builtin_fmaf(st[ni][ri], c1, cni + sg8[ri >> 2] + slm[ri & 3]);
            const float pp = __builtin_amdgcn_exp2f(e);
            if (ri & 1) ls1 += pp; else ls0 += pp;
            pv[ri] = pp;
          }
        } else {
#pragma unroll
          for (int ri = 0; ri < 16; ri++) {
            const int n = kb + ni * 32 + (ri & 3) + 8 * (ri >> 2) + 4 * hf;
            const float e = __builtin_fmaf(st[ni][ri], c1, cni + sg8[ri >> 2] + slm[ri & 3]);
            float pp = __builtin_amdgcn_exp2f(e);
            if (n > tg) pp = 0.f;
            if (ri & 1) ls1 += pp; else ls0 += pp;
            pv[ri] = pp;
          }
        }
        // packed f32->bf16 (replaces +0x8000 round + v_perm pair-packing)
        u32 pk[4][2];
#pragma unroll
        for (int g = 0; g < 4; g++) {
          pk[g][0] = cvtpk_bf16(pv[g * 4 + 0], pv[g * 4 + 1]);
          pk[g][1] = cvtpk_bf16(pv[g * 4 + 2], pv[g * 4 + 3]);
        }
#pragma unroll
        for (int a = 0; a < 2; a++) {
          const u32 snd0 = (hf == 0) ? pk[2 * a + 1][0] : pk[2 * a][0];
          const u32 snd1 = (hf == 0) ? pk[2 * a + 1][1] : pk[2 * a][1];
          const u32 rcv0 = (u32)__shfl_xor((int)snd0, 32);
          const u32 rcv1 = (u32)__shfl_xor((int)snd1, 32);
          u32x4 fr;
          fr.x = (hf == 0) ? pk[2 * a][0] : rcv0;
          fr.y = (hf == 0) ? pk[2 * a][1] : rcv1;
          fr.z = (hf == 0) ? rcv0 : pk[2 * a + 1][0];
          fr.w = (hf == 0) ? rcv1 : pk[2 * a + 1][1];
          pfrag[ni * 2 + a] = *(bf16x8*)&fr;
        }
      }

      // O += P * V
      __builtin_amdgcn_s_setprio(1);
#pragma unroll
      for (int kf16 = 0; kf16 < 8; kf16++) {
#pragma unroll
        for (int nd = 0; nd < 2; nd++) {
          bf16x8 vf = *(const bf16x8*)&Vtlds[(nd * 32 + qi) * VSTR + kf16 * 16 + hf * 8];
          oacc[nd] = mfma32(pfrag[kf16], vf, oacc[nd]);
        }
      }
      __builtin_amdgcn_s_setprio(0);
    }

    // combine key-halves of l within wave; write partials (no normalize).
    // Empty segments (p=0, s=1, segA) still write zeros: merge sums both slots.
    float lsum = ls0 + ls1;
    lsum += __shfl_xor(lsum, 32);
    if (hf == 0) lp[(size_t)s * 65536 + bh * Tdim + tg] = lsum;

    u16* Ob = Op + (size_t)s * (32u * Tdim * HD) + ((size_t)bh * Tdim) * HD;
#pragma unroll
    for (int nd = 0; nd < 2; nd++) {
#pragma unroll
      for (int ri = 0; ri < 16; ri++) {
        const int rq = (ri & 3) + 8 * (ri >> 2) + 4 * hf;
        const int t = q0 + w * 32 + rq;
        Ob[(size_t)t * HD + nd * 32 + qi] = f2bf(oacc[nd][ri]);
      }
    }
  }
}

// ---------------- merge partials + normalize -> AO bf16 ----------------
__global__ __launch_bounds__(256) void merge_k(const u16* __restrict__ Op,
                                               const float* __restrict__ lp,
                                               u16* __restrict__ AO) {
  const int i = blockIdx.x * 256 + threadIdx.x;  // octet index
  const int d8 = i & 7;
  const int t = (i >> 3) & 2047;
  const int bh = i >> 14;
  const int b = bh >> 4, h = bh & 15;
  const float l = lp[bh * Tdim + t] + lp[65536 + bh * Tdim + t];
  const float inv = 1.0f / l;
  const size_t off = ((size_t)bh * Tdim + t) * HD + d8 * 8;
  const u16* O0 = Op + off;
  const u16* O1 = Op + (size_t)32 * Tdim * HD + off;
  u16 outv[8];
#pragma unroll
  for (int j = 0; j < 8; j++)
    outv[j] = f2bf((bf2f(O0[j]) + bf2f(O1[j])) * inv);
  *(bf16x8*)&AO[((size_t)(b * Tdim + t)) * Ddim + h * HD + d8 * 8] = *(const bf16x8*)outv;
}

// ---------------- output projection GEMM: 64x128, BK=64, swizzled LDS (f32 out) ----------------
// Same T2/BK=64 treatment as gemm_qkv. A tile 64x64 (8KB), B 128x64 (16KB).
// 512 blocks = 2/CU. XCD swizzle: each XCD owns one full B-panel.
__global__ __launch_bounds__(256, 2) void gemm_out(
    const u16* __restrict__ A, const u16* __restrict__ WoT, const float* __restrict__ bo,
    float* __restrict__ C) {
  const int flat = blockIdx.x + 64 * blockIdx.y;
  const int l = (flat & 7) * 64 + (flat >> 3);
  const int lbx = l & 63, lby = l >> 6;

  __shared__ alignas(16) u16 Alds[64 * 64];
  __shared__ alignas(16) u16 Blds[128 * 64];
  const int tid = threadIdx.x;
  const int w = tid >> 6, lane = tid & 63, ln = lane & 15, quad = lane >> 4;
  const int tm = lbx * 64, tn = lby * 128;

  f32x4 acc[4][2] = {};

  const int srow = lane >> 3;
  const int scol = ((lane & 7) ^ srow) * 8;
  const u16* ag0 = A + (size_t)(tm + w * 16 + srow) * Ddim + scol;       // A: waves cover 16 rows x {j=0,1}
  const u16* bg0 = WoT + (size_t)(tn + w * 32 + srow) * Ddim + scol;     // B: waves cover 32 rows x {j=0..3}

  for (int k0 = 0; k0 < Ddim; k0 += 64) {
    __syncthreads();
#pragma unroll
    for (int j = 0; j < 2; j++)
      cp16(ag0 + (size_t)j * 8 * Ddim + k0, &Alds[(w * 16 + j * 8) * 64]);
#pragma unroll
    for (int j = 0; j < 4; j++)
      cp16(bg0 + (size_t)j * 8 * Ddim + k0, &Blds[(w * 32 + j * 8) * 64]);
    __syncthreads();
#pragma unroll
    for (int k2 = 0; k2 < 2; k2++) {
      const int so = ((k2 * 4 + quad) ^ (ln & 7)) * 8;
      bf16x8 af[4], bfr[2];
#pragma unroll
      for (int i = 0; i < 4; i++)
        af[i] = *(const bf16x8*)&Alds[(i * 16 + ln) * 64 + so];
#pragma unroll
      for (int i = 0; i < 2; i++)
        bfr[i] = *(const bf16x8*)&Blds[(w * 32 + i * 16 + ln) * 64 + so];
#pragma unroll
      for (int mi = 0; mi < 4; mi++)
#pragma unroll
        for (int ni = 0; ni < 2; ni++)
          acc[mi][ni] = mfma16(af[mi], bfr[ni], acc[mi][ni]);
    }
  }

#pragma unroll
  for (int mi = 0; mi < 4; mi++) {
#pragma unroll
    for (int ni = 0; ni < 2; ni++) {
      const int gm0 = tm + mi * 16 + quad * 4;
      const int gn = tn + w * 32 + ni * 16 + ln;
      const float bv_ = bo[gn];
#pragma unroll
      for (int r = 0; r < 4; r++)
        C[(size_t)(gm0 + r) * Ddim + gn] = acc[mi][ni][r] + bv_;
    }
  }
}

extern "C" void kernel_launch(void* const* d_in, const int* in_sizes, int n_in,
                              void* d_out, int out_size, void* d_ws, size_t ws_size,
                              hipStream_t stream) {
  (void)in_sizes; (void)n_in; (void)out_size; (void)ws_size;
  const float* x  = (const float*)d_in[0];
  const float* Wq = (const float*)d_in[1];
  const float* bq = (const float*)d_in[2];
  const float* Wk = (const float*)d_in[3];
  const float* bk = (const float*)d_in[4];
  const float* Wv = (const float*)d_in[5];
  const float* bv = (const float*)d_in[6];
  const float* Wo = (const float*)d_in[7];
  const float* bo = (const float*)d_in[8];

  char* ws = (char*)d_ws;
  const size_t MB = 1024 * 1024;
  u16* WT   = (u16*)(ws + 0 * MB);   // 8MB: WqT, WkT, WvT, WoT (z-major)
  u16* Qb   = (u16*)(ws + 8 * MB);   // 8MB bf16 (B,H,T,64)
  u16* Kb   = (u16*)(ws + 16 * MB);
  u16* Vtb  = (u16*)(ws + 24 * MB);  // 8MB bf16 (B,H,64,T)
  u16* Xb   = (u16*)(ws + 32 * MB);  // 8MB bf16 X; overlaps AO
  u16* AO   = (u16*)(ws + 32 * MB);  // 8MB bf16 (B,T,D)
  u16* Opart= (u16*)(ws + 40 * MB);  // 16MB: 2 x (BH,T,64) bf16 partial O
  float* lpart = (float*)(ws + 56 * MB); // 512KB: 2 x (BH,T) f32 partial l
  u16* WoT = WT + (size_t)3 * Ddim * Ddim;

  convert_x<<<dim3(2048), 256, 0, stream>>>(x, Xb);
  transpose_k<<<dim3(32, 32, 4), dim3(32, 8), 0, stream>>>(Wq, Wk, Wv, Wo, WT);

  gemm_qkv<<<dim3(32, 8, 3), 256, 0, stream>>>(Xb, WT, bq, bk, bv, Qb, Kb, Vtb);
  attn_k<<<dim3(512), 256, 0, stream>>>(Qb, Kb, Vtb, Opart, lpart);
  merge_k<<<dim3(2048), 256, 0, stream>>>(Opart, lpart, AO);
  gemm_out<<<dim3(64, 8), 256, 0, stream>>>(AO, WoT, bo, (float*)d_out);
}